// Round 11
// baseline (494.776 us; speedup 1.0000x reference)
//
#include <hip/hip_runtime.h>

typedef __attribute__((ext_vector_type(8))) short short8;
typedef __attribute__((ext_vector_type(8))) unsigned short ushort8;
typedef __attribute__((ext_vector_type(4))) float f32x4;
typedef __attribute__((ext_vector_type(4))) float float4v;
typedef __attribute__((ext_vector_type(4))) int int4v;

#define GLB_CAST(p) ((const __attribute__((address_space(1))) void*)(p))
#define LDS_CAST(p) ((__attribute__((address_space(3))) void*)(p))

__device__ __forceinline__ unsigned short f2bf_rne(float f) {
  unsigned u = __builtin_bit_cast(unsigned, f);
  u += 0x7fffu + ((u >> 16) & 1u);
  return (unsigned short)(u >> 16);
}

__device__ __forceinline__ bool w_looks_int32(const int* wi) {
  bool all_small = true;
#pragma unroll
  for (int i = 0; i < 16; ++i) {
    int v = wi[i];
    if (v > 127 || v < -128) all_small = false;
  }
  return all_small;
}

// ================= int8 pipeline =================

__global__ void pack_w_kernel(const void* __restrict__ w, int4v* __restrict__ wq, long n16) {
  const bool is32 = w_looks_int32((const int*)w);  // wave-uniform
  if (!is32) return;
  long stride = (long)gridDim.x * blockDim.x;
  for (long i = blockIdx.x * (long)blockDim.x + threadIdx.x; i < n16; i += stride) {
    const int4v* w4 = (const int4v*)w;
    int4v r;
#pragma unroll
    for (int qd = 0; qd < 4; ++qd) {
      int4v raw = w4[i * 4 + qd];
      r[qd] = (raw[0] & 0xff) | ((raw[1] & 0xff) << 8) | ((raw[2] & 0xff) << 16) | (raw[3] << 24);
    }
    wq[i] = r;
  }
}

// Fused per-row absmax + quantize (r7-verified): x read once, rowscale[row] = max|x_row|.
__global__ __launch_bounds__(256) void rowquant_kernel(const float* __restrict__ x,
                                                       int4v* __restrict__ q,
                                                       float* __restrict__ rowscale, int K) {
  const int row = blockIdx.x;
  const int tid = threadIdx.x;
  const float4v* xr = (const float4v*)(x + (long)row * K);

  float4v v[4];
  float m = 0.f;
#pragma unroll
  for (int i = 0; i < 4; ++i) {
    v[i] = xr[tid * 4 + i];
#pragma unroll
    for (int j = 0; j < 4; ++j) m = fmaxf(m, fabsf(v[i][j]));
  }
#pragma unroll
  for (int off = 32; off >= 1; off >>= 1) m = fmaxf(m, __shfl_xor(m, off));
  __shared__ float wmax[4];
  if ((tid & 63) == 0) wmax[tid >> 6] = m;
  __syncthreads();
  m = fmaxf(fmaxf(wmax[0], wmax[1]), fmaxf(wmax[2], wmax[3]));

  const float k = (m > 0.f) ? 127.f / m : 0.f;
  int4v r;
#pragma unroll
  for (int i = 0; i < 4; ++i) {
    int wv_ = 0;
#pragma unroll
    for (int j = 0; j < 4; ++j) {
      int b = (int)__builtin_rintf(v[i][j] * k);
      wv_ |= (b & 0xff) << (8 * j);
    }
    r[i] = wv_;
  }
  q[((long)row * K >> 4) + tid] = r;
  if (tid == 0) rowscale[row] = m;
}

// ====== 256x256 8-phase i8 GEMM, 16x16x64 MFMA, r11: ALL-READS-IN-P1 hoist ======
// C[m][n] = (sum_k A[m][k]*B[n][k]) * rowscale[m]*scaler/127, exact i32 accum.
// Verified invariants: BK=128 B rows, chunk'=chunk^(row&7) swizzle (conflicts==0, r3),
// XCD band remap (r4), STAGE slots + per-tile counted vmcnt(6) (r5/r7), setprio (T5),
// compiler counted lgkm waits (r10: explicit drain was null).
// r11 single change: ALL 24 ds_reads of tile t issue in phase 1 (consumption order
// afA, bf01, bf23, afB). Safe: whole tile t landed at tile start (vmcnt induction);
// all reads complete >=1 barrier before p2/p3/p4 STAGEs overwrite cur. Effect: q2-q4
// MFMA clusters carry no reads on their critical path; the ~2313 cyc/CU/tile of LDS
// traffic drains under the MFMA windows instead of serializing with them.
__global__ __launch_bounds__(512, 2) void gemm256_i8_kernel(
    const signed char* __restrict__ wraw, const signed char* __restrict__ wq,
    const signed char* __restrict__ A, float* __restrict__ C,
    const float* __restrict__ rowscale, const float* __restrict__ scaler,
    int M, int N, int K) {
  __shared__ __align__(16) char lds[131072];

  const signed char* Bw = w_looks_int32((const int*)wraw) ? wq : wraw;

  const int tid  = threadIdx.x;
  const int lane = tid & 63;
  const int wv   = tid >> 6;
  const int wm   = wv >> 2;
  const int wn   = wv & 3;
  const int fr   = lane & 15;
  const int fq   = lane >> 4;

  const int nwg  = gridDim.x;
  const int orig = blockIdx.x;
  const int ntn  = N >> 8;
  const int ntm  = M >> 8;
  int tm, tn;
  if (((nwg & 7) == 0) && ((ntm & 7) == 0)) {
    const int c     = orig & 7;
    const int w     = orig >> 3;
    const int bandh = ntm >> 3;
    tm = c * bandh + (w % bandh);
    tn = w / bandh;
  } else {
    tm = orig / ntn;
    tn = orig - tm * ntn;
  }
  const long rowBase = (long)tm << 8;
  const long colBase = (long)tn << 8;

  const int    srow  = tid >> 3;
  const int    scolb = (((tid & 7) ^ (srow & 7)) << 4);
  const size_t rowb  = (size_t)K;       // 4096 B per row (int8)
  const size_t hstep = rowb << 7;       // 128 rows
  const size_t r64   = rowb << 6;       // 64 rows
  const char*  gA    = (const char*)A + (rowBase + srow) * rowb + scolb;
  const char*  gB    = (const char*)Bw + (colBase + srow) * rowb + scolb;
  const int    dst   = tid << 4;

#define STAGE(gsrc, loff)                                                                              \
  do {                                                                                                 \
    __builtin_amdgcn_global_load_lds(GLB_CAST(gsrc), LDS_CAST(lds + (loff) + dst), 16, 0, 0);          \
    __builtin_amdgcn_global_load_lds(GLB_CAST((gsrc) + r64), LDS_CAST(lds + (loff) + 8192 + dst), 16, 0, 0); \
  } while (0)

  int offA[4][2], offB[2][2];
#pragma unroll
  for (int i = 0; i < 4; ++i) {
    const int lr = i * 32 + wm * 16 + fr;
    const int sw = (lr & 7) << 4;
#pragma unroll
    for (int kk = 0; kk < 2; ++kk) offA[i][kk] = lr * 128 + ((kk * 64 + fq * 16) ^ sw);
  }
#pragma unroll
  for (int j = 0; j < 2; ++j) {
    const int lr = j * 64 + wn * 16 + fr;
    const int sw = (lr & 7) << 4;
#pragma unroll
    for (int kk = 0; kk < 2; ++kk) offB[j][kk] = lr * 128 + ((kk * 64 + fq * 16) ^ sw);
  }

  int4v acc[8][4] = {};
  // Operand banks for the whole tile, read in consumption order at p1.
  int4v afA[4][2], afB[4][2], bf01[2][2], bf23[2][2];
  const int nt = K >> 7;  // BK=128

  STAGE(gA,         0);
  STAGE(gB,         32768);
  STAGE(gA + hstep, 16384);
  STAGE(gB + hstep, 49152);
  asm volatile("s_waitcnt vmcnt(4)" ::: "memory");
  if (nt > 1) {
    STAGE(gA + 128,         65536);
    STAGE(gB + 128,         65536 + 32768);
    STAGE(gA + hstep + 128, 65536 + 16384);
  }
  asm volatile("s_waitcnt vmcnt(6)" ::: "memory");
  __builtin_amdgcn_s_barrier();

  for (int t = 0; t < nt; ++t) {
    const int cur = (t & 1) << 16;
    const int nxt = cur ^ 65536;
    const size_t kof1 = (size_t)(t + 1) << 7;
    const size_t kof2 = (size_t)(t + 2) << 7;

    // ---- phase 1: read ALL 24 tile operands (consumption order); stage B1(t+1)->nxt
#pragma unroll
    for (int i = 0; i < 4; ++i) {               // q1 A-operands
      afA[i][0] = *(const int4v*)(lds + cur + offA[i][0]);
      afA[i][1] = *(const int4v*)(lds + cur + offA[i][1]);
    }
#pragma unroll
    for (int j = 0; j < 2; ++j) {               // q1/q4 B-operands
      bf01[j][0] = *(const int4v*)(lds + cur + 32768 + offB[j][0]);
      bf01[j][1] = *(const int4v*)(lds + cur + 32768 + offB[j][1]);
    }
#pragma unroll
    for (int j = 0; j < 2; ++j) {               // q2/q3 B-operands
      bf23[j][0] = *(const int4v*)(lds + cur + 49152 + offB[j][0]);
      bf23[j][1] = *(const int4v*)(lds + cur + 49152 + offB[j][1]);
    }
#pragma unroll
    for (int i = 0; i < 4; ++i) {               // q3/q4 A-operands
      afB[i][0] = *(const int4v*)(lds + cur + 16384 + offA[i][0]);
      afB[i][1] = *(const int4v*)(lds + cur + 16384 + offA[i][1]);
    }
    if (t + 1 < nt) STAGE(gB + hstep + kof1, nxt + 49152);
    __builtin_amdgcn_s_barrier();
    __builtin_amdgcn_s_setprio(1);
#pragma unroll
    for (int i = 0; i < 4; ++i)
#pragma unroll
      for (int j = 0; j < 2; ++j) {
        acc[i][j] = __builtin_amdgcn_mfma_i32_16x16x64_i8(afA[i][0], bf01[j][0], acc[i][j], 0, 0, 0);
        acc[i][j] = __builtin_amdgcn_mfma_i32_16x16x64_i8(afA[i][1], bf01[j][1], acc[i][j], 0, 0, 0);
      }
    __builtin_amdgcn_s_setprio(0);
    __builtin_amdgcn_s_barrier();

    // ---- phase 2: (no reads) stage A0(t+2)->cur; MFMA q2 = afA x bf23
    if (t + 2 < nt) STAGE(gA + kof2, cur + 0);
    __builtin_amdgcn_s_barrier();
    __builtin_amdgcn_s_setprio(1);
#pragma unroll
    for (int i = 0; i < 4; ++i)
#pragma unroll
      for (int j = 0; j < 2; ++j) {
        acc[i][2 + j] = __builtin_amdgcn_mfma_i32_16x16x64_i8(afA[i][0], bf23[j][0], acc[i][2 + j], 0, 0, 0);
        acc[i][2 + j] = __builtin_amdgcn_mfma_i32_16x16x64_i8(afA[i][1], bf23[j][1], acc[i][2 + j], 0, 0, 0);
      }
    __builtin_amdgcn_s_setprio(0);
    __builtin_amdgcn_s_barrier();

    // ---- phase 3: (no reads) stage B0(t+2)->cur; MFMA q3 = afB x bf23
    if (t + 2 < nt) STAGE(gB + kof2, cur + 32768);
    __builtin_amdgcn_s_barrier();
    __builtin_amdgcn_s_setprio(1);
#pragma unroll
    for (int i = 0; i < 4; ++i)
#pragma unroll
      for (int j = 0; j < 2; ++j) {
        acc[4 + i][2 + j] = __builtin_amdgcn_mfma_i32_16x16x64_i8(afB[i][0], bf23[j][0], acc[4 + i][2 + j], 0, 0, 0);
        acc[4 + i][2 + j] = __builtin_amdgcn_mfma_i32_16x16x64_i8(afB[i][1], bf23[j][1], acc[4 + i][2 + j], 0, 0, 0);
      }
    __builtin_amdgcn_s_setprio(0);
    __builtin_amdgcn_s_barrier();

    // ---- phase 4: stage A1(t+2)->cur; MFMA q4 = afB x bf01; counted vmcnt
    if (t + 2 < nt) STAGE(gA + hstep + kof2, cur + 16384);
    __builtin_amdgcn_s_barrier();
    __builtin_amdgcn_s_setprio(1);
#pragma unroll
    for (int i = 0; i < 4; ++i)
#pragma unroll
      for (int j = 0; j < 2; ++j) {
        acc[4 + i][j] = __builtin_amdgcn_mfma_i32_16x16x64_i8(afB[i][0], bf01[j][0], acc[4 + i][j], 0, 0, 0);
        acc[4 + i][j] = __builtin_amdgcn_mfma_i32_16x16x64_i8(afB[i][1], bf01[j][1], acc[4 + i][j], 0, 0, 0);
      }
    __builtin_amdgcn_s_setprio(0);
    if (t + 2 < nt)      { asm volatile("s_waitcnt vmcnt(6)" ::: "memory"); }
    else if (t + 1 < nt) { asm volatile("s_waitcnt vmcnt(0)" ::: "memory"); }
    if (t + 1 < nt) __builtin_amdgcn_s_barrier();
  }
#undef STAGE

  // Epilogue: D col = lane&15, row = (lane>>4)*4 + j; per-row scale.
  const float s = (*scaler) * (1.f / 127.f);
#pragma unroll
  for (int mi = 0; mi < 8; ++mi) {
#pragma unroll
    for (int j = 0; j < 4; ++j) {
      const long row = rowBase + mi * 32 + wm * 16 + fq * 4 + j;
      const float sc = rowscale[row] * s;
      float* cp = C + row * (long)N + colBase + wn * 16 + fr;
#pragma unroll
      for (int nj = 0; nj < 4; ++nj) cp[(size_t)nj * 64] = (float)acc[mi][nj][j] * sc;
    }
  }
}

// ================= bf16 fallback pipeline (verified r1-r4) =================

__global__ void cvt_x_kernel(const float* __restrict__ x, ushort8* __restrict__ xh, long n8) {
  long stride = (long)gridDim.x * blockDim.x;
  for (long i = blockIdx.x * (long)blockDim.x + threadIdx.x; i < n8; i += stride) {
    float4v a = reinterpret_cast<const float4v*>(x)[2 * i + 0];
    float4v b = reinterpret_cast<const float4v*>(x)[2 * i + 1];
    ushort8 r;
#pragma unroll
    for (int j = 0; j < 4; ++j) {
      r[j]     = f2bf_rne(a[j]);
      r[4 + j] = f2bf_rne(b[j]);
    }
    xh[i] = r;
  }
}

__global__ void cvt_w_kernel(const void* __restrict__ w, ushort8* __restrict__ wh,
                             const float* __restrict__ sp, long n16) {
  const float s = *sp;
  const bool is32 = w_looks_int32((const int*)w);
  long stride = (long)gridDim.x * blockDim.x;
  for (long i = blockIdx.x * (long)blockDim.x + threadIdx.x; i < n16; i += stride) {
    unsigned short tmp[16];
    if (is32) {
      const int4v* w4 = (const int4v*)w;
#pragma unroll
      for (int q = 0; q < 4; ++q) {
        int4v raw = w4[i * 4 + q];
#pragma unroll
        for (int j = 0; j < 4; ++j) tmp[4 * q + j] = f2bf_rne((float)raw[j] * s);
      }
    } else {
      int4v raw = reinterpret_cast<const int4v*>(w)[i];
#pragma unroll
      for (int q = 0; q < 4; ++q) {
        int v = raw[q];
        tmp[4 * q + 0] = f2bf_rne((float)(int)(signed char)(v & 0xff) * s);
        tmp[4 * q + 1] = f2bf_rne((float)(int)(signed char)((v >> 8) & 0xff) * s);
        tmp[4 * q + 2] = f2bf_rne((float)(int)(signed char)((v >> 16) & 0xff) * s);
        tmp[4 * q + 3] = f2bf_rne((float)(v >> 24) * s);
      }
    }
    ushort8 r0, r1;
#pragma unroll
    for (int j = 0; j < 8; ++j) { r0[j] = tmp[j]; r1[j] = tmp[8 + j]; }
    wh[2 * i + 0] = r0;
    wh[2 * i + 1] = r1;
  }
}

#define BM 128
#define BN 128
#define BK 32
__global__ __launch_bounds__(256) void gemm_bt_kernel(
    const unsigned short* __restrict__ A, const unsigned short* __restrict__ Bw,
    float* __restrict__ C, int M, int N, int K) {
  __shared__ __align__(16) unsigned short As[BM * BK];
  __shared__ __align__(16) unsigned short Bs[BN * BK];
  const int t = threadIdx.x, lane = t & 63, wv = t >> 6, wr = wv >> 1, wc = wv & 1;
  const long rowBase = (long)blockIdx.y * BM, colBase = (long)blockIdx.x * BN;
  const int r0 = t >> 2, cb0 = (t & 3) * 16, r1 = r0 + 64;
  const char* gA0 = (const char*)(A + (rowBase + r0) * (long)K) + cb0;
  const char* gA1 = (const char*)(A + (rowBase + r1) * (long)K) + cb0;
  const char* gB0 = (const char*)(Bw + (colBase + r0) * (long)K) + cb0;
  const char* gB1 = (const char*)(Bw + (colBase + r1) * (long)K) + cb0;
  char* lA0 = (char*)As + wv * 1024; char* lA1 = (char*)As + 4096 + wv * 1024;
  char* lB0 = (char*)Bs + wv * 1024; char* lB1 = (char*)Bs + 4096 + wv * 1024;
  const int fr = lane & 15, kb = (lane >> 4) * 16;
  const char* aBase = (const char*)As + (wr * 64 + fr) * (BK * 2) + kb;
  const char* bBase = (const char*)Bs + (wc * 64 + fr) * (BK * 2) + kb;
  f32x4 acc[4][4] = {};
  for (int k0 = 0; k0 < K; k0 += BK) {
    const long koff = (long)k0 * 2;
    __builtin_amdgcn_global_load_lds(GLB_CAST(gA0 + koff), LDS_CAST(lA0), 16, 0, 0);
    __builtin_amdgcn_global_load_lds(GLB_CAST(gA1 + koff), LDS_CAST(lA1), 16, 0, 0);
    __builtin_amdgcn_global_load_lds(GLB_CAST(gB0 + koff), LDS_CAST(lB0), 16, 0, 0);
    __builtin_amdgcn_global_load_lds(GLB_CAST(gB1 + koff), LDS_CAST(lB1), 16, 0, 0);
    __syncthreads();
    short8 af[4], bfv[4];
#pragma unroll
    for (int mi = 0; mi < 4; ++mi) af[mi] = *reinterpret_cast<const short8*>(aBase + mi * 16 * (BK * 2));
#pragma unroll
    for (int nj = 0; nj < 4; ++nj) bfv[nj] = *reinterpret_cast<const short8*>(bBase + nj * 16 * (BK * 2));
#pragma unroll
    for (int mi = 0; mi < 4; ++mi)
#pragma unroll
      for (int nj = 0; nj < 4; ++nj)
        acc[mi][nj] = __builtin_amdgcn_mfma_f32_16x16x32_bf16(af[mi], bfv[nj], acc[mi][nj], 0, 0, 0);
    __syncthreads();
  }
  const int fq = lane >> 4;
#pragma unroll
  for (int mi = 0; mi < 4; ++mi)
#pragma unroll
    for (int j = 0; j < 4; ++j) {
      const long row = rowBase + wr * 64 + mi * 16 + fq * 4 + j;
      float* cp = C + row * (long)N + colBase + wc * 64 + fr;
#pragma unroll
      for (int nj = 0; nj < 4; ++nj) cp[nj * 16] = acc[mi][nj][j];
    }
}

__global__ void gemm_naive_kernel(const float* __restrict__ x, const void* __restrict__ w,
                                  const float* __restrict__ sp, float* __restrict__ out,
                                  int M, int N, int K) {
  const bool is32 = w_looks_int32((const int*)w);
  int n = blockIdx.x * 16 + threadIdx.x;
  int m = blockIdx.y * 16 + threadIdx.y;
  if (m >= M || n >= N) return;
  const float* xr = x + (long)m * K;
  float acc = 0.f;
  if (is32) {
    const int* wr_ = (const int*)w + (long)n * K;
    for (int k = 0; k < K; ++k) acc += xr[k] * (float)wr_[k];
  } else {
    const signed char* wr_ = (const signed char*)w + (long)n * K;
    for (int k = 0; k < K; ++k) acc += xr[k] * (float)wr_[k];
  }
  out[(long)m * N + n] = acc * (*sp);
}

extern "C" void kernel_launch(void* const* d_in, const int* in_sizes, int n_in,
                              void* d_out, int out_size, void* d_ws, size_t ws_size,
                              hipStream_t stream) {
  const float* x      = (const float*)d_in[0];
  const void*  w      = (const void*)d_in[1];
  const float* scaler = (const float*)d_in[2];
  float*       out    = (float*)d_out;

  const int K = 4096;
  const int N = 11008;
  const int M = in_sizes[0] / K;

  const size_t xq_bytes = (size_t)M * K;
  const size_t wq_bytes = (size_t)N * K;
  const size_t rs_bytes = (size_t)M * 4;
  const size_t i8_need  = xq_bytes + wq_bytes + rs_bytes + 64;

  if ((M % 256 == 0) && (N % 256 == 0) && (K == 4096) && ws_size >= i8_need) {
    signed char* xq = (signed char*)d_ws;
    signed char* wq = (signed char*)((char*)d_ws + xq_bytes);
    float*       rs = (float*)((char*)d_ws + xq_bytes + wq_bytes);

    pack_w_kernel<<<512, 256, 0, stream>>>(w, (int4v*)wq, (long)N * K / 16);
    rowquant_kernel<<<M, 256, 0, stream>>>(x, (int4v*)xq, rs, K);
    gemm256_i8_kernel<<<dim3((M / 256) * (N / 256)), 512, 0, stream>>>(
        (const signed char*)w, wq, xq, out, rs, scaler, M, N, K);
    return;
  }

  const size_t xh_bytes = (size_t)M * K * 2;
  const size_t wh_bytes = (size_t)N * K * 2;
  if (ws_size < xh_bytes + wh_bytes) {
    dim3 g((N + 15) / 16, (M + 15) / 16), b(16, 16);
    gemm_naive_kernel<<<g, b, 0, stream>>>(x, w, scaler, out, M, N, K);
    return;
  }

  unsigned short* xh = (unsigned short*)d_ws;
  unsigned short* wh = (unsigned short*)((char*)d_ws + xh_bytes);
  cvt_x_kernel<<<2048, 256, 0, stream>>>(x, (ushort8*)xh, (long)M * K / 8);
  cvt_w_kernel<<<2048, 256, 0, stream>>>(w, (ushort8*)wh, scaler, (long)N * K / 16);
  gemm_bt_kernel<<<dim3(N / BN, M / BM), 256, 0, stream>>>(xh, wh, out, M, N, K);
}

// Round 12
// 473.892 us; speedup vs baseline: 1.0441x; 1.0441x over previous
//
#include <hip/hip_runtime.h>

typedef __attribute__((ext_vector_type(8))) short short8;
typedef __attribute__((ext_vector_type(8))) unsigned short ushort8;
typedef __attribute__((ext_vector_type(4))) float f32x4;
typedef __attribute__((ext_vector_type(4))) float float4v;
typedef __attribute__((ext_vector_type(4))) int int4v;

#define GLB_CAST(p) ((const __attribute__((address_space(1))) void*)(p))
#define LDS_CAST(p) ((__attribute__((address_space(3))) void*)(p))

__device__ __forceinline__ unsigned short f2bf_rne(float f) {
  unsigned u = __builtin_bit_cast(unsigned, f);
  u += 0x7fffu + ((u >> 16) & 1u);
  return (unsigned short)(u >> 16);
}

__device__ __forceinline__ bool w_looks_int32(const int* wi) {
  bool all_small = true;
#pragma unroll
  for (int i = 0; i < 16; ++i) {
    int v = wi[i];
    if (v > 127 || v < -128) all_small = false;
  }
  return all_small;
}

// ================= int8 pipeline =================

__global__ void pack_w_kernel(const void* __restrict__ w, int4v* __restrict__ wq, long n16) {
  const bool is32 = w_looks_int32((const int*)w);  // wave-uniform
  if (!is32) return;
  long stride = (long)gridDim.x * blockDim.x;
  for (long i = blockIdx.x * (long)blockDim.x + threadIdx.x; i < n16; i += stride) {
    const int4v* w4 = (const int4v*)w;
    int4v r;
#pragma unroll
    for (int qd = 0; qd < 4; ++qd) {
      int4v raw = w4[i * 4 + qd];
      r[qd] = (raw[0] & 0xff) | ((raw[1] & 0xff) << 8) | ((raw[2] & 0xff) << 16) | (raw[3] << 24);
    }
    wq[i] = r;
  }
}

// Fused per-row absmax + quantize, r12: chunked coalesced access.
// Thread t reads float4 #t of each 1024-float chunk (lane-contiguous 16B reads)
// and writes one packed dword per chunk (lane-contiguous 4B writes). Quantized
// values and rowscale identical to r7's version (same elements, same math).
__global__ __launch_bounds__(256) void rowquant_kernel(const float* __restrict__ x,
                                                       int* __restrict__ q,
                                                       float* __restrict__ rowscale, int K) {
  const int row = blockIdx.x;
  const int tid = threadIdx.x;
  const float4v* xr = (const float4v*)(x + (long)row * K);  // K/4 = 1024 float4

  float4v v[4];
  float m = 0.f;
#pragma unroll
  for (int c = 0; c < 4; ++c) {
    v[c] = xr[c * 256 + tid];
#pragma unroll
    for (int j = 0; j < 4; ++j) m = fmaxf(m, fabsf(v[c][j]));
  }
#pragma unroll
  for (int off = 32; off >= 1; off >>= 1) m = fmaxf(m, __shfl_xor(m, off));
  __shared__ float wmax[4];
  if ((tid & 63) == 0) wmax[tid >> 6] = m;
  __syncthreads();
  m = fmaxf(fmaxf(wmax[0], wmax[1]), fmaxf(wmax[2], wmax[3]));

  const float k = (m > 0.f) ? 127.f / m : 0.f;
  int* qr = q + (long)row * (K >> 2);  // 1024 dwords per row
#pragma unroll
  for (int c = 0; c < 4; ++c) {
    int wv_ = 0;
#pragma unroll
    for (int j = 0; j < 4; ++j) {
      int b = (int)__builtin_rintf(v[c][j] * k);
      wv_ |= (b & 0xff) << (8 * j);
    }
    qr[c * 256 + tid] = wv_;
  }
  if (tid == 0) rowscale[row] = m;
}

// ============ 256x256 8-phase i8 GEMM, 16x16x64 MFMA (r10 verified-best) ============
// C[m][n] = (sum_k A[m][k]*B[n][k]) * rowscale[m]*scaler/127, exact i32 accumulation.
// Verified invariants: BK=128 B rows, chunk'=chunk^(row&7) swizzle (conflicts==0, r3),
// XCD band remap (r4), STAGE slots + per-tile counted vmcnt(6) (r5/r7), setprio (T5),
// compiler counted lgkm waits (r10). Schedule probes r8/r9/r11 (unroll, read-ahead,
// read-hoist) all null/regressed -> this is the measured-best configuration
// (GEMM ~405 us, MfmaUtil ~40%, ~46% of i8 pipe steady-state).
__global__ __launch_bounds__(512, 2) void gemm256_i8_kernel(
    const signed char* __restrict__ wraw, const signed char* __restrict__ wq,
    const signed char* __restrict__ A, float* __restrict__ C,
    const float* __restrict__ rowscale, const float* __restrict__ scaler,
    int M, int N, int K) {
  __shared__ __align__(16) char lds[131072];

  const signed char* Bw = w_looks_int32((const int*)wraw) ? wq : wraw;

  const int tid  = threadIdx.x;
  const int lane = tid & 63;
  const int wv   = tid >> 6;
  const int wm   = wv >> 2;
  const int wn   = wv & 3;
  const int fr   = lane & 15;
  const int fq   = lane >> 4;

  const int nwg  = gridDim.x;
  const int orig = blockIdx.x;
  const int ntn  = N >> 8;
  const int ntm  = M >> 8;
  int tm, tn;
  if (((nwg & 7) == 0) && ((ntm & 7) == 0)) {
    const int c     = orig & 7;
    const int w     = orig >> 3;
    const int bandh = ntm >> 3;
    tm = c * bandh + (w % bandh);
    tn = w / bandh;
  } else {
    tm = orig / ntn;
    tn = orig - tm * ntn;
  }
  const long rowBase = (long)tm << 8;
  const long colBase = (long)tn << 8;

  const int    srow  = tid >> 3;
  const int    scolb = (((tid & 7) ^ (srow & 7)) << 4);
  const size_t rowb  = (size_t)K;       // 4096 B per row (int8)
  const size_t hstep = rowb << 7;       // 128 rows
  const size_t r64   = rowb << 6;       // 64 rows
  const char*  gA    = (const char*)A + (rowBase + srow) * rowb + scolb;
  const char*  gB    = (const char*)Bw + (colBase + srow) * rowb + scolb;
  const int    dst   = tid << 4;

#define STAGE(gsrc, loff)                                                                              \
  do {                                                                                                 \
    __builtin_amdgcn_global_load_lds(GLB_CAST(gsrc), LDS_CAST(lds + (loff) + dst), 16, 0, 0);          \
    __builtin_amdgcn_global_load_lds(GLB_CAST((gsrc) + r64), LDS_CAST(lds + (loff) + 8192 + dst), 16, 0, 0); \
  } while (0)

  int offA[4][2], offB[2][2];
#pragma unroll
  for (int i = 0; i < 4; ++i) {
    const int lr = i * 32 + wm * 16 + fr;
    const int sw = (lr & 7) << 4;
#pragma unroll
    for (int kk = 0; kk < 2; ++kk) offA[i][kk] = lr * 128 + ((kk * 64 + fq * 16) ^ sw);
  }
#pragma unroll
  for (int j = 0; j < 2; ++j) {
    const int lr = j * 64 + wn * 16 + fr;
    const int sw = (lr & 7) << 4;
#pragma unroll
    for (int kk = 0; kk < 2; ++kk) offB[j][kk] = lr * 128 + ((kk * 64 + fq * 16) ^ sw);
  }

  int4v acc[8][4] = {};
  int4v af[4][2], bf[4][2];
  const int nt = K >> 7;  // BK=128

  STAGE(gA,         0);
  STAGE(gB,         32768);
  STAGE(gA + hstep, 16384);
  STAGE(gB + hstep, 49152);
  asm volatile("s_waitcnt vmcnt(4)" ::: "memory");
  if (nt > 1) {
    STAGE(gA + 128,         65536);
    STAGE(gB + 128,         65536 + 32768);
    STAGE(gA + hstep + 128, 65536 + 16384);
  }
  asm volatile("s_waitcnt vmcnt(6)" ::: "memory");
  __builtin_amdgcn_s_barrier();

  for (int t = 0; t < nt; ++t) {
    const int cur = (t & 1) << 16;
    const int nxt = cur ^ 65536;
    const size_t kof1 = (size_t)(t + 1) << 7;
    const size_t kof2 = (size_t)(t + 2) << 7;

    // ---- phase 1: read A m0-3 (A-half0) + B n0-1 (B-half0); stage B1(t+1)->nxt
#pragma unroll
    for (int i = 0; i < 4; ++i) {
      af[i][0] = *(const int4v*)(lds + cur + offA[i][0]);
      af[i][1] = *(const int4v*)(lds + cur + offA[i][1]);
    }
#pragma unroll
    for (int j = 0; j < 2; ++j) {
      bf[j][0] = *(const int4v*)(lds + cur + 32768 + offB[j][0]);
      bf[j][1] = *(const int4v*)(lds + cur + 32768 + offB[j][1]);
    }
    if (t + 1 < nt) STAGE(gB + hstep + kof1, nxt + 49152);
    __builtin_amdgcn_s_barrier();
    __builtin_amdgcn_s_setprio(1);
#pragma unroll
    for (int i = 0; i < 4; ++i)
#pragma unroll
      for (int j = 0; j < 2; ++j) {
        acc[i][j] = __builtin_amdgcn_mfma_i32_16x16x64_i8(af[i][0], bf[j][0], acc[i][j], 0, 0, 0);
        acc[i][j] = __builtin_amdgcn_mfma_i32_16x16x64_i8(af[i][1], bf[j][1], acc[i][j], 0, 0, 0);
      }
    __builtin_amdgcn_s_setprio(0);
    __builtin_amdgcn_s_barrier();

    // ---- phase 2: read B n2-3 (B-half1); stage A0(t+2)->cur
#pragma unroll
    for (int j = 2; j < 4; ++j) {
      bf[j][0] = *(const int4v*)(lds + cur + 49152 + offB[j - 2][0]);
      bf[j][1] = *(const int4v*)(lds + cur + 49152 + offB[j - 2][1]);
    }
    if (t + 2 < nt) STAGE(gA + kof2, cur + 0);
    __builtin_amdgcn_s_barrier();
    __builtin_amdgcn_s_setprio(1);
#pragma unroll
    for (int i = 0; i < 4; ++i)
#pragma unroll
      for (int j = 2; j < 4; ++j) {
        acc[i][j] = __builtin_amdgcn_mfma_i32_16x16x64_i8(af[i][0], bf[j][0], acc[i][j], 0, 0, 0);
        acc[i][j] = __builtin_amdgcn_mfma_i32_16x16x64_i8(af[i][1], bf[j][1], acc[i][j], 0, 0, 0);
      }
    __builtin_amdgcn_s_setprio(0);
    __builtin_amdgcn_s_barrier();

    // ---- phase 3: read A m4-7 (A-half1); stage B0(t+2)->cur
#pragma unroll
    for (int i = 0; i < 4; ++i) {
      af[i][0] = *(const int4v*)(lds + cur + 16384 + offA[i][0]);
      af[i][1] = *(const int4v*)(lds + cur + 16384 + offA[i][1]);
    }
    if (t + 2 < nt) STAGE(gB + kof2, cur + 32768);
    __builtin_amdgcn_s_barrier();
    __builtin_amdgcn_s_setprio(1);
#pragma unroll
    for (int i = 0; i < 4; ++i)
#pragma unroll
      for (int j = 2; j < 4; ++j) {
        acc[4 + i][j] = __builtin_amdgcn_mfma_i32_16x16x64_i8(af[i][0], bf[j][0], acc[4 + i][j], 0, 0, 0);
        acc[4 + i][j] = __builtin_amdgcn_mfma_i32_16x16x64_i8(af[i][1], bf[j][1], acc[4 + i][j], 0, 0, 0);
      }
    __builtin_amdgcn_s_setprio(0);
    __builtin_amdgcn_s_barrier();

    // ---- phase 4: stage A1(t+2)->cur; MFMA m4-7 x n0-1; counted vmcnt
    if (t + 2 < nt) STAGE(gA + hstep + kof2, cur + 16384);
    __builtin_amdgcn_s_barrier();
    __builtin_amdgcn_s_setprio(1);
#pragma unroll
    for (int i = 0; i < 4; ++i)
#pragma unroll
      for (int j = 0; j < 2; ++j) {
        acc[4 + i][j] = __builtin_amdgcn_mfma_i32_16x16x64_i8(af[i][0], bf[j][0], acc[4 + i][j], 0, 0, 0);
        acc[4 + i][j] = __builtin_amdgcn_mfma_i32_16x16x64_i8(af[i][1], bf[j][1], acc[4 + i][j], 0, 0, 0);
      }
    __builtin_amdgcn_s_setprio(0);
    if (t + 2 < nt)      { asm volatile("s_waitcnt vmcnt(6)" ::: "memory"); }
    else if (t + 1 < nt) { asm volatile("s_waitcnt vmcnt(0)" ::: "memory"); }
    if (t + 1 < nt) __builtin_amdgcn_s_barrier();
  }
#undef STAGE

  // Epilogue: D col = lane&15, row = (lane>>4)*4 + j; per-row scale.
  const float s = (*scaler) * (1.f / 127.f);
#pragma unroll
  for (int mi = 0; mi < 8; ++mi) {
#pragma unroll
    for (int j = 0; j < 4; ++j) {
      const long row = rowBase + mi * 32 + wm * 16 + fq * 4 + j;
      const float sc = rowscale[row] * s;
      float* cp = C + row * (long)N + colBase + wn * 16 + fr;
#pragma unroll
      for (int nj = 0; nj < 4; ++nj) cp[(size_t)nj * 64] = (float)acc[mi][nj][j] * sc;
    }
  }
}

// ================= bf16 fallback pipeline (verified r1-r4) =================

__global__ void cvt_x_kernel(const float* __restrict__ x, ushort8* __restrict__ xh, long n8) {
  long stride = (long)gridDim.x * blockDim.x;
  for (long i = blockIdx.x * (long)blockDim.x + threadIdx.x; i < n8; i += stride) {
    float4v a = reinterpret_cast<const float4v*>(x)[2 * i + 0];
    float4v b = reinterpret_cast<const float4v*>(x)[2 * i + 1];
    ushort8 r;
#pragma unroll
    for (int j = 0; j < 4; ++j) {
      r[j]     = f2bf_rne(a[j]);
      r[4 + j] = f2bf_rne(b[j]);
    }
    xh[i] = r;
  }
}

__global__ void cvt_w_kernel(const void* __restrict__ w, ushort8* __restrict__ wh,
                             const float* __restrict__ sp, long n16) {
  const float s = *sp;
  const bool is32 = w_looks_int32((const int*)w);
  long stride = (long)gridDim.x * blockDim.x;
  for (long i = blockIdx.x * (long)blockDim.x + threadIdx.x; i < n16; i += stride) {
    unsigned short tmp[16];
    if (is32) {
      const int4v* w4 = (const int4v*)w;
#pragma unroll
      for (int q = 0; q < 4; ++q) {
        int4v raw = w4[i * 4 + q];
#pragma unroll
        for (int j = 0; j < 4; ++j) tmp[4 * q + j] = f2bf_rne((float)raw[j] * s);
      }
    } else {
      int4v raw = reinterpret_cast<const int4v*>(w)[i];
#pragma unroll
      for (int q = 0; q < 4; ++q) {
        int v = raw[q];
        tmp[4 * q + 0] = f2bf_rne((float)(int)(signed char)(v & 0xff) * s);
        tmp[4 * q + 1] = f2bf_rne((float)(int)(signed char)((v >> 8) & 0xff) * s);
        tmp[4 * q + 2] = f2bf_rne((float)(int)(signed char)((v >> 16) & 0xff) * s);
        tmp[4 * q + 3] = f2bf_rne((float)(v >> 24) * s);
      }
    }
    ushort8 r0, r1;
#pragma unroll
    for (int j = 0; j < 8; ++j) { r0[j] = tmp[j]; r1[j] = tmp[8 + j]; }
    wh[2 * i + 0] = r0;
    wh[2 * i + 1] = r1;
  }
}

#define BM 128
#define BN 128
#define BK 32
__global__ __launch_bounds__(256) void gemm_bt_kernel(
    const unsigned short* __restrict__ A, const unsigned short* __restrict__ Bw,
    float* __restrict__ C, int M, int N, int K) {
  __shared__ __align__(16) unsigned short As[BM * BK];
  __shared__ __align__(16) unsigned short Bs[BN * BK];
  const int t = threadIdx.x, lane = t & 63, wv = t >> 6, wr = wv >> 1, wc = wv & 1;
  const long rowBase = (long)blockIdx.y * BM, colBase = (long)blockIdx.x * BN;
  const int r0 = t >> 2, cb0 = (t & 3) * 16, r1 = r0 + 64;
  const char* gA0 = (const char*)(A + (rowBase + r0) * (long)K) + cb0;
  const char* gA1 = (const char*)(A + (rowBase + r1) * (long)K) + cb0;
  const char* gB0 = (const char*)(Bw + (colBase + r0) * (long)K) + cb0;
  const char* gB1 = (const char*)(Bw + (colBase + r1) * (long)K) + cb0;
  char* lA0 = (char*)As + wv * 1024; char* lA1 = (char*)As + 4096 + wv * 1024;
  char* lB0 = (char*)Bs + wv * 1024; char* lB1 = (char*)Bs + 4096 + wv * 1024;
  const int fr = lane & 15, kb = (lane >> 4) * 16;
  const char* aBase = (const char*)As + (wr * 64 + fr) * (BK * 2) + kb;
  const char* bBase = (const char*)Bs + (wc * 64 + fr) * (BK * 2) + kb;
  f32x4 acc[4][4] = {};
  for (int k0 = 0; k0 < K; k0 += BK) {
    const long koff = (long)k0 * 2;
    __builtin_amdgcn_global_load_lds(GLB_CAST(gA0 + koff), LDS_CAST(lA0), 16, 0, 0);
    __builtin_amdgcn_global_load_lds(GLB_CAST(gA1 + koff), LDS_CAST(lA1), 16, 0, 0);
    __builtin_amdgcn_global_load_lds(GLB_CAST(gB0 + koff), LDS_CAST(lB0), 16, 0, 0);
    __builtin_amdgcn_global_load_lds(GLB_CAST(gB1 + koff), LDS_CAST(lB1), 16, 0, 0);
    __syncthreads();
    short8 af[4], bfv[4];
#pragma unroll
    for (int mi = 0; mi < 4; ++mi) af[mi] = *reinterpret_cast<const short8*>(aBase + mi * 16 * (BK * 2));
#pragma unroll
    for (int nj = 0; nj < 4; ++nj) bfv[nj] = *reinterpret_cast<const short8*>(bBase + nj * 16 * (BK * 2));
#pragma unroll
    for (int mi = 0; mi < 4; ++mi)
#pragma unroll
      for (int nj = 0; nj < 4; ++nj)
        acc[mi][nj] = __builtin_amdgcn_mfma_f32_16x16x32_bf16(af[mi], bfv[nj], acc[mi][nj], 0, 0, 0);
    __syncthreads();
  }
  const int fq = lane >> 4;
#pragma unroll
  for (int mi = 0; mi < 4; ++mi)
#pragma unroll
    for (int j = 0; j < 4; ++j) {
      const long row = rowBase + wr * 64 + mi * 16 + fq * 4 + j;
      float* cp = C + row * (long)N + colBase + wc * 64 + fr;
#pragma unroll
      for (int nj = 0; nj < 4; ++nj) cp[nj * 16] = acc[mi][nj][j];
    }
}

__global__ void gemm_naive_kernel(const float* __restrict__ x, const void* __restrict__ w,
                                  const float* __restrict__ sp, float* __restrict__ out,
                                  int M, int N, int K) {
  const bool is32 = w_looks_int32((const int*)w);
  int n = blockIdx.x * 16 + threadIdx.x;
  int m = blockIdx.y * 16 + threadIdx.y;
  if (m >= M || n >= N) return;
  const float* xr = x + (long)m * K;
  float acc = 0.f;
  if (is32) {
    const int* wr_ = (const int*)w + (long)n * K;
    for (int k = 0; k < K; ++k) acc += xr[k] * (float)wr_[k];
  } else {
    const signed char* wr_ = (const signed char*)w + (long)n * K;
    for (int k = 0; k < K; ++k) acc += xr[k] * (float)wr_[k];
  }
  out[(long)m * N + n] = acc * (*sp);
}

extern "C" void kernel_launch(void* const* d_in, const int* in_sizes, int n_in,
                              void* d_out, int out_size, void* d_ws, size_t ws_size,
                              hipStream_t stream) {
  const float* x      = (const float*)d_in[0];
  const void*  w      = (const void*)d_in[1];
  const float* scaler = (const float*)d_in[2];
  float*       out    = (float*)d_out;

  const int K = 4096;
  const int N = 11008;
  const int M = in_sizes[0] / K;

  const size_t xq_bytes = (size_t)M * K;
  const size_t wq_bytes = (size_t)N * K;
  const size_t rs_bytes = (size_t)M * 4;
  const size_t i8_need  = xq_bytes + wq_bytes + rs_bytes + 64;

  if ((M % 256 == 0) && (N % 256 == 0) && (K == 4096) && ws_size >= i8_need) {
    signed char* xq = (signed char*)d_ws;
    signed char* wq = (signed char*)((char*)d_ws + xq_bytes);
    float*       rs = (float*)((char*)d_ws + xq_bytes + wq_bytes);

    pack_w_kernel<<<512, 256, 0, stream>>>(w, (int4v*)wq, (long)N * K / 16);
    rowquant_kernel<<<M, 256, 0, stream>>>(x, (int*)xq, rs, K);
    gemm256_i8_kernel<<<dim3((M / 256) * (N / 256)), 512, 0, stream>>>(
        (const signed char*)w, wq, xq, out, rs, scaler, M, N, K);
    return;
  }

  const size_t xh_bytes = (size_t)M * K * 2;
  const size_t wh_bytes = (size_t)N * K * 2;
  if (ws_size < xh_bytes + wh_bytes) {
    dim3 g((N + 15) / 16, (M + 15) / 16), b(16, 16);
    gemm_naive_kernel<<<g, b, 0, stream>>>(x, w, scaler, out, M, N, K);
    return;
  }

  unsigned short* xh = (unsigned short*)d_ws;
  unsigned short* wh = (unsigned short*)((char*)d_ws + xh_bytes);
  cvt_x_kernel<<<2048, 256, 0, stream>>>(x, (ushort8*)xh, (long)M * K / 8);
  cvt_w_kernel<<<2048, 256, 0, stream>>>(w, (ushort8*)wh, scaler, (long)N * K / 16);
  gemm_bt_kernel<<<dim3(N / BN, M / BM), 256, 0, stream>>>(xh, wh, out, M, N, K);
}

// Round 13
// 472.879 us; speedup vs baseline: 1.0463x; 1.0021x over previous
//
#include <hip/hip_runtime.h>

typedef __attribute__((ext_vector_type(8))) short short8;
typedef __attribute__((ext_vector_type(8))) unsigned short ushort8;
typedef __attribute__((ext_vector_type(4))) float f32x4;
typedef __attribute__((ext_vector_type(4))) float float4v;
typedef __attribute__((ext_vector_type(4))) int int4v;

#define GLB_CAST(p) ((const __attribute__((address_space(1))) void*)(p))
#define LDS_CAST(p) ((__attribute__((address_space(3))) void*)(p))

__device__ __forceinline__ unsigned short f2bf_rne(float f) {
  unsigned u = __builtin_bit_cast(unsigned, f);
  u += 0x7fffu + ((u >> 16) & 1u);
  return (unsigned short)(u >> 16);
}

__device__ __forceinline__ bool w_looks_int32(const int* wi) {
  bool all_small = true;
#pragma unroll
  for (int i = 0; i < 16; ++i) {
    int v = wi[i];
    if (v > 127 || v < -128) all_small = false;
  }
  return all_small;
}

// ================= int8 pipeline =================

__global__ void pack_w_kernel(const void* __restrict__ w, int4v* __restrict__ wq, long n16) {
  const bool is32 = w_looks_int32((const int*)w);  // wave-uniform
  if (!is32) return;
  long stride = (long)gridDim.x * blockDim.x;
  for (long i = blockIdx.x * (long)blockDim.x + threadIdx.x; i < n16; i += stride) {
    const int4v* w4 = (const int4v*)w;
    int4v r;
#pragma unroll
    for (int qd = 0; qd < 4; ++qd) {
      int4v raw = w4[i * 4 + qd];
      r[qd] = (raw[0] & 0xff) | ((raw[1] & 0xff) << 8) | ((raw[2] & 0xff) << 16) | (raw[3] << 24);
    }
    wq[i] = r;
  }
}

// Fused per-row absmax + quantize (r12 coalesced form).
__global__ __launch_bounds__(256) void rowquant_kernel(const float* __restrict__ x,
                                                       int* __restrict__ q,
                                                       float* __restrict__ rowscale, int K) {
  const int row = blockIdx.x;
  const int tid = threadIdx.x;
  const float4v* xr = (const float4v*)(x + (long)row * K);  // K/4 = 1024 float4

  float4v v[4];
  float m = 0.f;
#pragma unroll
  for (int c = 0; c < 4; ++c) {
    v[c] = xr[c * 256 + tid];
#pragma unroll
    for (int j = 0; j < 4; ++j) m = fmaxf(m, fabsf(v[c][j]));
  }
#pragma unroll
  for (int off = 32; off >= 1; off >>= 1) m = fmaxf(m, __shfl_xor(m, off));
  __shared__ float wmax[4];
  if ((tid & 63) == 0) wmax[tid >> 6] = m;
  __syncthreads();
  m = fmaxf(fmaxf(wmax[0], wmax[1]), fmaxf(wmax[2], wmax[3]));

  const float k = (m > 0.f) ? 127.f / m : 0.f;
  int* qr = q + (long)row * (K >> 2);
#pragma unroll
  for (int c = 0; c < 4; ++c) {
    int wv_ = 0;
#pragma unroll
    for (int j = 0; j < 4; ++j) {
      int b = (int)__builtin_rintf(v[c][j] * k);
      wv_ |= (b & 0xff) << (8 * j);
    }
    qr[c * 256 + tid] = wv_;
  }
  if (tid == 0) rowscale[row] = m;
}

// ====== r13: 128x128 i8 GEMM, 4 waves, SINGLE-buffer, 2 blocks/CU ======
// Rationale: the 256^2 8-phase kernel is pinned at 1 block/CU (acc=128 AGPR/wave)
// so all waves share ONE barrier group -> LDS-read windows and MFMA windows
// serialize (r8-r11 all null/regressed). Here acc=64 regs/wave -> 2 independent
// blocks/CU: when one block is in its read/stage/barrier window, the other's
// MFMAs fill the matrix pipe (m114 co-scheduling). Sync shape = the r0-r4
// verified 2-barrier gemm_bt template; swizzle chunk'=chunk^(row&7) (conflicts==0,
// r3), XCD band remap (r4), per-row scale epilogue (r7) all carried over.
__global__ __launch_bounds__(256, 2) void gemm128_i8_kernel(
    const signed char* __restrict__ wraw, const signed char* __restrict__ wq,
    const signed char* __restrict__ A, float* __restrict__ C,
    const float* __restrict__ rowscale, const float* __restrict__ scaler,
    int M, int N, int K) {
  __shared__ __align__(16) char lds[32768];  // A[128][128B] @0, B[128][128B] @16384

  const signed char* Bw = w_looks_int32((const int*)wraw) ? wq : wraw;

  const int tid  = threadIdx.x;
  const int lane = tid & 63;
  const int wv   = tid >> 6;   // 0..3
  const int wm   = wv >> 1;    // 0..1
  const int wn   = wv & 1;     // 0..1
  const int fr   = lane & 15;
  const int fq   = lane >> 4;

  // XCD band remap (bandh tm-rows per XCD, tm fastest within band).
  const int nwg  = gridDim.x;
  const int orig = blockIdx.x;
  const int ntn  = N >> 7;
  const int ntm  = M >> 7;
  int tm, tn;
  if (((nwg & 7) == 0) && ((ntm & 7) == 0)) {
    const int c     = orig & 7;
    const int w     = orig >> 3;
    const int bandh = ntm >> 3;
    tm = c * bandh + (w % bandh);
    tn = w / bandh;
  } else {
    tm = orig / ntn;
    tn = orig - tm * ntn;
  }
  const long rowBase = (long)tm << 7;
  const long colBase = (long)tn << 7;

  // Staging: 256 threads x 16 B cover 32 rows (4 KB) per issue; 4 issues per array.
  // Thread t writes stored chunk (t&7) of row (t>>3)+32s; inverse-swizzled source.
  const int    srow  = tid >> 3;                          // 0..31
  const int    scolb = (((tid & 7) ^ (srow & 7)) << 4);   // (row+32)&7 == row&7
  const size_t rowb  = (size_t)K;                         // 4096 B per row
  const size_t r32   = rowb << 5;                         // 32-row step
  const char*  gA    = (const char*)A + (rowBase + srow) * rowb + scolb;
  const char*  gB    = (const char*)Bw + (colBase + srow) * rowb + scolb;
  const int    dst   = tid << 4;

#define STAGE_TILE(koff)                                                                                \
  do {                                                                                                  \
    _Pragma("unroll") for (int s = 0; s < 4; ++s)                                                       \
      __builtin_amdgcn_global_load_lds(GLB_CAST(gA + (koff) + s * r32),                                 \
                                       LDS_CAST(lds + s * 4096 + dst), 16, 0, 0);                       \
    _Pragma("unroll") for (int s = 0; s < 4; ++s)                                                       \
      __builtin_amdgcn_global_load_lds(GLB_CAST(gB + (koff) + s * r32),                                 \
                                       LDS_CAST(lds + 16384 + s * 4096 + dst), 16, 0, 0);               \
  } while (0)

  // Per-wave 64x64 output: A rows wm*64 + i*16 + fr, B rows wn*64 + j*16 + fr.
  int offA[4][2], offB[4][2];
#pragma unroll
  for (int i = 0; i < 4; ++i) {
    const int lr = wm * 64 + i * 16 + fr;
    const int sw = (lr & 7) << 4;
#pragma unroll
    for (int kk = 0; kk < 2; ++kk) offA[i][kk] = lr * 128 + ((kk * 64 + fq * 16) ^ sw);
  }
#pragma unroll
  for (int j = 0; j < 4; ++j) {
    const int lr = wn * 64 + j * 16 + fr;
    const int sw = (lr & 7) << 4;
#pragma unroll
    for (int kk = 0; kk < 2; ++kk) offB[j][kk] = lr * 128 + ((kk * 64 + fq * 16) ^ sw);
  }

  int4v acc[4][4] = {};  // 64 regs -> 2 blocks/CU
  int4v af[4][2], bf[4][2];
  const int nt = K >> 7;  // BK=128

  STAGE_TILE(0);
  __syncthreads();  // compiler drains vmcnt(0) before barrier -> tile 0 landed

  for (int t = 0; t < nt; ++t) {
    // reads: whole tile's operands into regs
#pragma unroll
    for (int i = 0; i < 4; ++i) {
      af[i][0] = *(const int4v*)(lds + offA[i][0]);
      af[i][1] = *(const int4v*)(lds + offA[i][1]);
    }
#pragma unroll
    for (int j = 0; j < 4; ++j) {
      bf[j][0] = *(const int4v*)(lds + 16384 + offB[j][0]);
      bf[j][1] = *(const int4v*)(lds + 16384 + offB[j][1]);
    }
    __syncthreads();  // all waves done reading -> safe to overwrite buffer

    if (t + 1 < nt) STAGE_TILE((size_t)(t + 1) << 7);  // loads fly under MFMA window

    __builtin_amdgcn_s_setprio(1);
#pragma unroll
    for (int i = 0; i < 4; ++i)
#pragma unroll
      for (int j = 0; j < 4; ++j) {
        acc[i][j] = __builtin_amdgcn_mfma_i32_16x16x64_i8(af[i][0], bf[j][0], acc[i][j], 0, 0, 0);
        acc[i][j] = __builtin_amdgcn_mfma_i32_16x16x64_i8(af[i][1], bf[j][1], acc[i][j], 0, 0, 0);
      }
    __builtin_amdgcn_s_setprio(0);

    __syncthreads();  // drains vmcnt(0) -> tile t+1 landed for all waves
  }
#undef STAGE_TILE

  // Epilogue: D col = lane&15, row = (lane>>4)*4 + jj (verified layout); per-row scale.
  const float s = (*scaler) * (1.f / 127.f);
#pragma unroll
  for (int i = 0; i < 4; ++i) {
#pragma unroll
    for (int jj = 0; jj < 4; ++jj) {
      const long row = rowBase + wm * 64 + i * 16 + fq * 4 + jj;
      const float sc = rowscale[row] * s;
      float* cp = C + row * (long)N + colBase + wn * 64 + fr;
#pragma unroll
      for (int j = 0; j < 4; ++j) cp[(size_t)j * 16] = (float)acc[i][j][jj] * sc;
    }
  }
}

// ================= bf16 fallback pipeline (verified r1-r4) =================

__global__ void cvt_x_kernel(const float* __restrict__ x, ushort8* __restrict__ xh, long n8) {
  long stride = (long)gridDim.x * blockDim.x;
  for (long i = blockIdx.x * (long)blockDim.x + threadIdx.x; i < n8; i += stride) {
    float4v a = reinterpret_cast<const float4v*>(x)[2 * i + 0];
    float4v b = reinterpret_cast<const float4v*>(x)[2 * i + 1];
    ushort8 r;
#pragma unroll
    for (int j = 0; j < 4; ++j) {
      r[j]     = f2bf_rne(a[j]);
      r[4 + j] = f2bf_rne(b[j]);
    }
    xh[i] = r;
  }
}

__global__ void cvt_w_kernel(const void* __restrict__ w, ushort8* __restrict__ wh,
                             const float* __restrict__ sp, long n16) {
  const float s = *sp;
  const bool is32 = w_looks_int32((const int*)w);
  long stride = (long)gridDim.x * blockDim.x;
  for (long i = blockIdx.x * (long)blockDim.x + threadIdx.x; i < n16; i += stride) {
    unsigned short tmp[16];
    if (is32) {
      const int4v* w4 = (const int4v*)w;
#pragma unroll
      for (int q = 0; q < 4; ++q) {
        int4v raw = w4[i * 4 + q];
#pragma unroll
        for (int j = 0; j < 4; ++j) tmp[4 * q + j] = f2bf_rne((float)raw[j] * s);
      }
    } else {
      int4v raw = reinterpret_cast<const int4v*>(w)[i];
#pragma unroll
      for (int q = 0; q < 4; ++q) {
        int v = raw[q];
        tmp[4 * q + 0] = f2bf_rne((float)(int)(signed char)(v & 0xff) * s);
        tmp[4 * q + 1] = f2bf_rne((float)(int)(signed char)((v >> 8) & 0xff) * s);
        tmp[4 * q + 2] = f2bf_rne((float)(int)(signed char)((v >> 16) & 0xff) * s);
        tmp[4 * q + 3] = f2bf_rne((float)(v >> 24) * s);
      }
    }
    ushort8 r0, r1;
#pragma unroll
    for (int j = 0; j < 8; ++j) { r0[j] = tmp[j]; r1[j] = tmp[8 + j]; }
    wh[2 * i + 0] = r0;
    wh[2 * i + 1] = r1;
  }
}

#define BM 128
#define BN 128
#define BK 32
__global__ __launch_bounds__(256) void gemm_bt_kernel(
    const unsigned short* __restrict__ A, const unsigned short* __restrict__ Bw,
    float* __restrict__ C, int M, int N, int K) {
  __shared__ __align__(16) unsigned short As[BM * BK];
  __shared__ __align__(16) unsigned short Bs[BN * BK];
  const int t = threadIdx.x, lane = t & 63, wv = t >> 6, wr = wv >> 1, wc = wv & 1;
  const long rowBase = (long)blockIdx.y * BM, colBase = (long)blockIdx.x * BN;
  const int r0 = t >> 2, cb0 = (t & 3) * 16, r1 = r0 + 64;
  const char* gA0 = (const char*)(A + (rowBase + r0) * (long)K) + cb0;
  const char* gA1 = (const char*)(A + (rowBase + r1) * (long)K) + cb0;
  const char* gB0 = (const char*)(Bw + (colBase + r0) * (long)K) + cb0;
  const char* gB1 = (const char*)(Bw + (colBase + r1) * (long)K) + cb0;
  char* lA0 = (char*)As + wv * 1024; char* lA1 = (char*)As + 4096 + wv * 1024;
  char* lB0 = (char*)Bs + wv * 1024; char* lB1 = (char*)Bs + 4096 + wv * 1024;
  const int fr = lane & 15, kb = (lane >> 4) * 16;
  const char* aBase = (const char*)As + (wr * 64 + fr) * (BK * 2) + kb;
  const char* bBase = (const char*)Bs + (wc * 64 + fr) * (BK * 2) + kb;
  f32x4 acc[4][4] = {};
  for (int k0 = 0; k0 < K; k0 += BK) {
    const long koff = (long)k0 * 2;
    __builtin_amdgcn_global_load_lds(GLB_CAST(gA0 + koff), LDS_CAST(lA0), 16, 0, 0);
    __builtin_amdgcn_global_load_lds(GLB_CAST(gA1 + koff), LDS_CAST(lA1), 16, 0, 0);
    __builtin_amdgcn_global_load_lds(GLB_CAST(gB0 + koff), LDS_CAST(lB0), 16, 0, 0);
    __builtin_amdgcn_global_load_lds(GLB_CAST(gB1 + koff), LDS_CAST(lB1), 16, 0, 0);
    __syncthreads();
    short8 af[4], bfv[4];
#pragma unroll
    for (int mi = 0; mi < 4; ++mi) af[mi] = *reinterpret_cast<const short8*>(aBase + mi * 16 * (BK * 2));
#pragma unroll
    for (int nj = 0; nj < 4; ++nj) bfv[nj] = *reinterpret_cast<const short8*>(bBase + nj * 16 * (BK * 2));
#pragma unroll
    for (int mi = 0; mi < 4; ++mi)
#pragma unroll
      for (int nj = 0; nj < 4; ++nj)
        acc[mi][nj] = __builtin_amdgcn_mfma_f32_16x16x32_bf16(af[mi], bfv[nj], acc[mi][nj], 0, 0, 0);
    __syncthreads();
  }
  const int fq = lane >> 4;
#pragma unroll
  for (int mi = 0; mi < 4; ++mi)
#pragma unroll
    for (int j = 0; j < 4; ++j) {
      const long row = rowBase + wr * 64 + mi * 16 + fq * 4 + j;
      float* cp = C + row * (long)N + colBase + wc * 64 + fr;
#pragma unroll
      for (int nj = 0; nj < 4; ++nj) cp[nj * 16] = acc[mi][nj][j];
    }
}

__global__ void gemm_naive_kernel(const float* __restrict__ x, const void* __restrict__ w,
                                  const float* __restrict__ sp, float* __restrict__ out,
                                  int M, int N, int K) {
  const bool is32 = w_looks_int32((const int*)w);
  int n = blockIdx.x * 16 + threadIdx.x;
  int m = blockIdx.y * 16 + threadIdx.y;
  if (m >= M || n >= N) return;
  const float* xr = x + (long)m * K;
  float acc = 0.f;
  if (is32) {
    const int* wr_ = (const int*)w + (long)n * K;
    for (int k = 0; k < K; ++k) acc += xr[k] * (float)wr_[k];
  } else {
    const signed char* wr_ = (const signed char*)w + (long)n * K;
    for (int k = 0; k < K; ++k) acc += xr[k] * (float)wr_[k];
  }
  out[(long)m * N + n] = acc * (*sp);
}

extern "C" void kernel_launch(void* const* d_in, const int* in_sizes, int n_in,
                              void* d_out, int out_size, void* d_ws, size_t ws_size,
                              hipStream_t stream) {
  const float* x      = (const float*)d_in[0];
  const void*  w      = (const void*)d_in[1];
  const float* scaler = (const float*)d_in[2];
  float*       out    = (float*)d_out;

  const int K = 4096;
  const int N = 11008;
  const int M = in_sizes[0] / K;

  const size_t xq_bytes = (size_t)M * K;
  const size_t wq_bytes = (size_t)N * K;
  const size_t rs_bytes = (size_t)M * 4;
  const size_t i8_need  = xq_bytes + wq_bytes + rs_bytes + 64;

  if ((M % 128 == 0) && (N % 128 == 0) && (K == 4096) && ws_size >= i8_need) {
    signed char* xq = (signed char*)d_ws;
    signed char* wq = (signed char*)((char*)d_ws + xq_bytes);
    float*       rs = (float*)((char*)d_ws + xq_bytes + wq_bytes);

    pack_w_kernel<<<512, 256, 0, stream>>>(w, (int4v*)wq, (long)N * K / 16);
    rowquant_kernel<<<M, 256, 0, stream>>>(x, (int*)xq, rs, K);
    gemm128_i8_kernel<<<dim3((M / 128) * (N / 128)), 256, 0, stream>>>(
        (const signed char*)w, wq, xq, out, rs, scaler, M, N, K);
    return;
  }

  const size_t xh_bytes = (size_t)M * K * 2;
  const size_t wh_bytes = (size_t)N * K * 2;
  if (ws_size < xh_bytes + wh_bytes) {
    dim3 g((N + 15) / 16, (M + 15) / 16), b(16, 16);
    gemm_naive_kernel<<<g, b, 0, stream>>>(x, w, scaler, out, M, N, K);
    return;
  }

  unsigned short* xh = (unsigned short*)d_ws;
  unsigned short* wh = (unsigned short*)((char*)d_ws + xh_bytes);
  cvt_x_kernel<<<2048, 256, 0, stream>>>(x, (ushort8*)xh, (long)M * K / 8);
  cvt_w_kernel<<<2048, 256, 0, stream>>>(w, (ushort8*)wh, scaler, (long)N * K / 16);
  gemm_bt_kernel<<<dim3(N / BN, M / BM), 256, 0, stream>>>(xh, wh, out, M, N, K);
}